// Round 17
// baseline (345.412 us; speedup 1.0000x reference)
//
#include <hip/hip_runtime.h>

#define NUM_TAG 1024
#define TAG_DIM 128
#define NROWS   131072      // B*W = 128*1024
#define FLAG_M  5.5e-4f     // h-only margin, ~7 sigma (verified r14/r15, absmax 0)
#define RPG     16          // rows per group in exact_fix
#define RF      4           // 16-row A fragments per wave (64 rows/wave)

typedef __attribute__((ext_vector_type(8))) short short8;
typedef __attribute__((ext_vector_type(4))) float f32x4;

// Exact 2-way bf16 split: x = h + m + (residual < 2^-16 |x|), h/m bf16-exact.
__device__ inline void split2(float xv, unsigned short& h, unsigned short& m) {
    unsigned xb = __float_as_uint(xv);
    unsigned hb = xb & 0xFFFF0000u;
    float r1 = xv - __uint_as_float(hb);        // Sterbenz-exact
    unsigned mb = __float_as_uint(r1) & 0xFFFF0000u;
    h = (unsigned short)(hb >> 16);
    m = (unsigned short)(mb >> 16);
}

// async global->LDS, 16B per lane (linear LDS dest = wave-uniform base + lane*16)
__device__ inline void gld_lds16(const void* g, void* l) {
    __builtin_amdgcn_global_load_lds(
        (const __attribute__((address_space(1))) void*)g,
        (__attribute__((address_space(3))) void*)l, 16, 0, 0);
}

// -------- fused prep: h-only frag codebook + fp32 transposed codebook + scc ----
// Chunk = 32 codes, h-only: 2 c x 4 s x 64 lanes x 8 elems = 4096 ushorts = 8 KB.
// 32 chunks = 256 KB. cbf[ch*4096 + ((c*4 + s)*64 + l)*8 + e]
//   = truncbf16(cb[ch*32 + c*16 + (l&15)][s*32 + (l>>4)*8 + e])
// cbT[d*1024 + k] = cb[k][d]   (fp32 transpose, r15/r16-verified, for exact_fix)
__global__ __launch_bounds__(256) void prep_kernel(
    const float* __restrict__ cb, float* __restrict__ scc,
    unsigned short* __restrict__ cbf, float* __restrict__ cbT,
    int* __restrict__ count)
{
    int t = blockIdx.x * 256 + threadIdx.x;   // 16384 threads
    if (t == 0) count[0] = 0;
    {
        int l  = t & 63;
        int s  = (t >> 6) & 3;
        int c  = (t >> 8) & 1;
        int ch = t >> 9;                       // 0..31
        int k  = ch * 32 + c * 16 + (l & 15);
        int d0 = s * 32 + (l >> 4) * 8;
        const float4* xp = reinterpret_cast<const float4*>(cb) + k * 32 + (d0 >> 2);
        float4 v0 = xp[0], v1 = xp[1];
        float xv[8] = {v0.x, v0.y, v0.z, v0.w, v1.x, v1.y, v1.z, v1.w};
        short8 hh;
#pragma unroll
        for (int e = 0; e < 8; ++e) {
            hh[e] = (short)(unsigned short)(__float_as_uint(xv[e]) >> 16);
            cbT[(d0 + e) * 1024 + k] = xv[e];
        }
        *reinterpret_cast<short8*>(cbf + (long)ch * 4096 + (((c * 4 + s) * 64 + l) * 8)) = hh;
    }
    if (t < NUM_TAG) {
        const float4* row = reinterpret_cast<const float4*>(cb) + t * (TAG_DIM / 4);
        float s = 0.f;
#pragma unroll
        for (int i = 0; i < TAG_DIM / 4; ++i) {
            float4 v = row[i];
            s += v.x * v.x; s += v.y * v.y; s += v.z * v.z; s += v.w * v.w;
        }
        scc[t] = s;
    }
}

// -------- pass A: (Ah+Am)xBh MFMA scores + top-2 + near-tie flag append --------
// r12/r16's verified no-barrier skeleton (ONE wave per block, 2048 blocks,
// gld_lds double buffer of 8 KB chunks, counted vmcnt(8) never 0 in-loop,
// lgkmcnt(0) WAR fence, sched_barrier(0) per rule #18) with h-only chunks of
// 32 codes: 64 MFMAs/chunk (vs r16's 48), 32 chunks (vs 64), 2 products.
// Product order per (s,c): Am.Bh then Ah.Bh (verified r14/r15). Fold med3 form
// identical to r9-r16. scc from LDS (lgkm path; vmcnt FIFO = staging only).
__global__ __launch_bounds__(64, 2) void argmin_mfma_kernel(
    const float* __restrict__ x,
    const unsigned short* __restrict__ cbf,
    const float* __restrict__ scc,
    float* __restrict__ fidx_out,
    int* __restrict__ list, int* __restrict__ count)
{
    __shared__ __align__(16) unsigned short lds[2][4096];   // 2 x 8 KB
    __shared__ float scc_lds[NUM_TAG];                      // 4 KB  (20 KB total)

    const int l   = threadIdx.x & 63;
    const int l15 = l & 15;
    const int l4  = l >> 4;
    const int row0 = blockIdx.x * 64;

    const float4* gsrc = reinterpret_cast<const float4*>(cbf);  // chunk = 512 float4

    // ---- prologue staging: scc (4 loads) then chunks 0,1 (8+8) ----
#pragma unroll
    for (int i = 0; i < 4; ++i)
        gld_lds16(reinterpret_cast<const float4*>(scc) + i * 64 + l,
                  (void*)(scc_lds + (i * 64 + l) * 4));
#pragma unroll
    for (int i = 0; i < 8; ++i)
        gld_lds16(gsrc + i * 64 + l, (void*)&lds[0][(i * 64 + l) * 8]);
#pragma unroll
    for (int i = 0; i < 8; ++i)
        gld_lds16(gsrc + 512 + i * 64 + l, (void*)&lds[1][(i * 64 + l) * 8]);

    // ---- A fragments (these loads drain the whole vmcnt FIFO via split2 use) --
    short8 Ah[RF][4], Am[RF][4];
#pragma unroll
    for (int rf = 0; rf < RF; ++rf) {
        const float4* xp = reinterpret_cast<const float4*>(x) +
                           (long)(row0 + rf * 16 + l15) * 32 + l4 * 2;
#pragma unroll
        for (int s = 0; s < 4; ++s) {
            float4 v0 = xp[s * 8];
            float4 v1 = xp[s * 8 + 1];
            float xv[8] = {v0.x, v0.y, v0.z, v0.w, v1.x, v1.y, v1.z, v1.w};
#pragma unroll
            for (int e = 0; e < 8; ++e) {
                unsigned short h, m;
                split2(xv[e], h, m);
                Ah[rf][s][e] = (short)h;
                Am[rf][s][e] = (short)m;
            }
        }
    }

    float m1[RF][4], m2[RF][4]; int i1[RF][4];
#pragma unroll
    for (int rf = 0; rf < RF; ++rf)
#pragma unroll
        for (int r = 0; r < 4; ++r) { m1[rf][r] = 3.4e38f; m2[rf][r] = 3.4e38f; i1[rf][r] = 0; }

    for (int ch = 0; ch < 32; ++ch) {
        const int b = ch & 1;
        // current chunk guaranteed in LDS: <=8 outstanding leaves only next chunk
        if (ch < 31) { asm volatile("s_waitcnt vmcnt(8)" ::: "memory"); }
        else         { asm volatile("s_waitcnt vmcnt(0)" ::: "memory"); }
        __builtin_amdgcn_sched_barrier(0);

        // LDS -> registers: 8 x ds_read_b128 (B frags) + 2 x ds_read_b32 (scc)
        short8 Bh[2][4];
#pragma unroll
        for (int c = 0; c < 2; ++c)
#pragma unroll
            for (int s = 0; s < 4; ++s)
                Bh[c][s] = *reinterpret_cast<const short8*>(
                    &lds[b][(((c * 4 + s) * 64 + l) * 8)]);
        const float sccv0 = scc_lds[ch * 32 + 0 * 16 + l15];
        const float sccv1 = scc_lds[ch * 32 + 1 * 16 + l15];

        // all LDS reads landed in regs before we overwrite this buffer (WAR)
        asm volatile("s_waitcnt lgkmcnt(0)" ::: "memory");
        __builtin_amdgcn_sched_barrier(0);

        // re-stage this buffer with chunk ch+2
        if (ch + 2 < 32) {
            const float4* gp = gsrc + (ch + 2) * 512 + l;
#pragma unroll
            for (int i = 0; i < 8; ++i)
                gld_lds16(gp + i * 64, (void*)&lds[b][(i * 64 + l) * 8]);
        }

        f32x4 acc[RF][2];
#pragma unroll
        for (int rf = 0; rf < RF; ++rf)
#pragma unroll
            for (int c = 0; c < 2; ++c) acc[rf][c] = (f32x4)0.f;

        // verified r14/r15 order: s ascending, (Am,Bh) then (Ah,Bh)
#pragma unroll
        for (int s = 0; s < 4; ++s)
#pragma unroll
            for (int c = 0; c < 2; ++c)
#pragma unroll
                for (int rf = 0; rf < RF; ++rf) {
                    acc[rf][c] = __builtin_amdgcn_mfma_f32_16x16x32_bf16(Am[rf][s], Bh[c][s], acc[rf][c], 0, 0, 0);
                    acc[rf][c] = __builtin_amdgcn_mfma_f32_16x16x32_bf16(Ah[rf][s], Bh[c][s], acc[rf][c], 0, 0, 0);
                }

        // fold into running top-2 (med3 form, verified r9-r16)
#pragma unroll
        for (int c = 0; c < 2; ++c) {
            const int k = ch * 32 + c * 16 + l15;
            const float sccv = c ? sccv1 : sccv0;
#pragma unroll
            for (int rf = 0; rf < RF; ++rf)
#pragma unroll
                for (int r = 0; r < 4; ++r) {
                    float score = sccv - 2.0f * acc[rf][c][r];
                    m2[rf][r] = __builtin_amdgcn_fmed3f(score, m1[rf][r], m2[rf][r]);
                    i1[rf][r] = (score < m1[rf][r]) ? k : i1[rf][r];
                    m1[rf][r] = fminf(m1[rf][r], score);
                }
        }
    }

    // ---- cross-lane top-2 merge within each 16-lane col group ----
#pragma unroll
    for (int rf = 0; rf < RF; ++rf)
#pragma unroll
        for (int r = 0; r < 4; ++r) {
            float v1 = m1[rf][r], v2 = m2[rf][r]; int ii = i1[rf][r];
#pragma unroll
            for (int mk = 1; mk < 16; mk <<= 1) {
                float o1 = __shfl_xor(v1, mk, 64);
                float o2 = __shfl_xor(v2, mk, 64);
                int   oi = __shfl_xor(ii, mk, 64);
                float n2 = fminf(fminf(v2, o2), fmaxf(v1, o1));  // global 2nd-min
                if (o1 < v1 || (o1 == v1 && oi < ii)) { v1 = o1; ii = oi; }
                v2 = n2;
            }
            if (l15 == 0) {
                int row = row0 + rf * 16 + l4 * 4 + r;
                fidx_out[row] = (float)ii;
                if (v2 - v1 <= FLAG_M) {           // near-tie: append for exact rescore
                    int pos = atomicAdd(count, 1); // list order nondet; per-row results
                    list[pos] = row;               // independent -> output deterministic
                }
            }
        }
}

// -------- pass B: exact rescore, coalesced via transposed codebook (r15/r16) --
// Thread tid owns codes k = j*256+tid (j ascending -> in-thread ascending k).
// Per (row,code): fma chain in d-ascending order (one fma per d) == round-1
// recipe bit-exactly. dist = (sxx+scc) - 2*dot, tie -> lowest k (lex reduces).
__global__ __launch_bounds__(256) void exact_fix_kernel(
    const float* __restrict__ x, const float* __restrict__ cbT,
    const float* __restrict__ scc, const int* __restrict__ list,
    const int* __restrict__ count, float* __restrict__ fidx_out)
{
    __shared__ float Xs[RPG][TAG_DIM];   // 8 KB
    __shared__ float sxxs[RPG];
    __shared__ float wrv[RPG][4];
    __shared__ int   wri[RPG][4];
    __shared__ int   rows_s[RPG];

    const int tid  = threadIdx.x;
    const int lane = tid & 63;
    const int wv   = tid >> 6;
    const int nflag = count[0];
    const int ngroups = (nflag + RPG - 1) / RPG;

    for (int g = blockIdx.x; g < ngroups; g += gridDim.x) {
        const int nr = min(RPG, nflag - g * RPG);
        if (tid < RPG)
            rows_s[tid] = list[g * RPG + min(tid, nr - 1)];   // dup last for tail
        __syncthreads();
        // stage RPG rows x 32 float4 (coalesced)
        for (int t2 = tid; t2 < RPG * 32; t2 += 256) {
            int r = t2 >> 5, i = t2 & 31;
            reinterpret_cast<float4*>(&Xs[r][0])[i] =
                reinterpret_cast<const float4*>(x)[(long)rows_s[r] * 32 + i];
        }
        __syncthreads();
        if (tid < RPG) {   // per-row sxx, round-1 sequential order
            float s = 0.f;
            for (int i = 0; i < 32; ++i) {
                float4 v = reinterpret_cast<float4*>(&Xs[tid][0])[i];
                s += v.x * v.x; s += v.y * v.y; s += v.z * v.z; s += v.w * v.w;
            }
            sxxs[tid] = s;
        }
        __syncthreads();

        float acc[RPG][4];
#pragma unroll
        for (int r = 0; r < RPG; ++r)
#pragma unroll
            for (int j = 0; j < 4; ++j) acc[r][j] = 0.f;

        for (int d4 = 0; d4 < 32; ++d4) {
            float4 xq[RPG];
#pragma unroll
            for (int r = 0; r < RPG; ++r)
                xq[r] = reinterpret_cast<float4*>(&Xs[r][0])[d4];
#pragma unroll
            for (int e = 0; e < 4; ++e) {
                const int d = d4 * 4 + e;
                float c0 = cbT[d * 1024 + 0 * 256 + tid];   // coalesced
                float c1 = cbT[d * 1024 + 1 * 256 + tid];
                float c2 = cbT[d * 1024 + 2 * 256 + tid];
                float c3 = cbT[d * 1024 + 3 * 256 + tid];
#pragma unroll
                for (int r = 0; r < RPG; ++r) {
                    float xv = (e == 0) ? xq[r].x : (e == 1) ? xq[r].y
                             : (e == 2) ? xq[r].z : xq[r].w;
                    acc[r][0] += xv * c0;   // d-ascending fma chain (== round-1)
                    acc[r][1] += xv * c1;
                    acc[r][2] += xv * c2;
                    acc[r][3] += xv * c3;
                }
            }
        }

#pragma unroll
        for (int r = 0; r < RPG; ++r) {
            float bv = 3.4e38f; int bi = 0;
            const float sxxv = sxxs[r];
#pragma unroll
            for (int j = 0; j < 4; ++j) {
                int k = j * 256 + tid;             // in-thread ascending k
                float s1 = sxxv + scc[k];          // np: (sxx + scc)
                float dist = s1 - 2.0f * acc[r][j]; // np: ... - 2*dot
                if (dist < bv) { bv = dist; bi = k; }
            }
            // wave reduce (tie -> lowest k)
#pragma unroll
            for (int mk = 1; mk < 64; mk <<= 1) {
                float ov = __shfl_xor(bv, mk, 64);
                int   oi = __shfl_xor(bi, mk, 64);
                if (ov < bv || (ov == bv && oi < bi)) { bv = ov; bi = oi; }
            }
            if (lane == 0) { wrv[r][wv] = bv; wri[r][wv] = bi; }
        }
        __syncthreads();
        if (tid < RPG && tid < nr) {
            float bv = wrv[tid][0]; int bi = wri[tid][0];
#pragma unroll
            for (int e = 1; e < 4; ++e) {
                float v = wrv[tid][e]; int oi = wri[tid][e];
                if (v < bv || (v == bv && oi < bi)) { bv = v; bi = oi; }
            }
            fidx_out[rows_s[tid]] = (float)bi;
        }
        __syncthreads();
    }
}

// -------- phase 2: gather + STE output + loss partials --------
__global__ __launch_bounds__(256) void quant_kernel(
    const float* __restrict__ x, const float* __restrict__ cb,
    const float* __restrict__ fidx, float* __restrict__ out,
    double* __restrict__ partial)
{
    const int N4 = NROWS * (TAG_DIM / 4);
    double s = 0.0;
    for (int i = blockIdx.x * blockDim.x + threadIdx.x; i < N4; i += gridDim.x * blockDim.x) {
        int n = i >> 5;
        int d4 = i & 31;
        int k = (int)fidx[n];
        float4 xv = reinterpret_cast<const float4*>(x)[i];
        float4 qv = reinterpret_cast<const float4*>(cb)[k * 32 + d4];
        float dx = qv.x - xv.x, dy = qv.y - xv.y, dz = qv.z - xv.z, dw = qv.w - xv.w;
        float4 o;
        o.x = xv.x + dx; o.y = xv.y + dy; o.z = xv.z + dz; o.w = xv.w + dw;
        reinterpret_cast<float4*>(out)[i] = o;
        s += (double)dx * dx; s += (double)dy * dy; s += (double)dz * dz; s += (double)dw * dw;
    }
    __shared__ double sd[256];
    sd[threadIdx.x] = s;
    __syncthreads();
    for (int off = 128; off > 0; off >>= 1) {
        if (threadIdx.x < (unsigned)off) sd[threadIdx.x] += sd[threadIdx.x + off];
        __syncthreads();
    }
    if (threadIdx.x == 0) partial[blockIdx.x] = sd[0];
}

__global__ __launch_bounds__(256) void loss_kernel(
    const double* __restrict__ partial, int n, float* __restrict__ out_loss)
{
    __shared__ double sd[256];
    double s = 0.0;
    for (int i = threadIdx.x; i < n; i += 256) s += partial[i];
    sd[threadIdx.x] = s;
    __syncthreads();
    for (int off = 128; off > 0; off >>= 1) {
        if (threadIdx.x < (unsigned)off) sd[threadIdx.x] += sd[threadIdx.x + off];
        __syncthreads();
    }
    if (threadIdx.x == 0) {
        double mean = sd[0] / (double)((long long)NROWS * TAG_DIM);
        out_loss[0] = (float)(mean + 0.25 * mean);
    }
}

extern "C" void kernel_launch(void* const* d_in, const int* in_sizes, int n_in,
                              void* d_out, int out_size, void* d_ws, size_t ws_size,
                              hipStream_t stream) {
    const float* x  = (const float*)d_in[0];   // [131072][128]
    const float* cb = (const float*)d_in[1];   // [1024][128]
    float* out      = (float*)d_out;
    float* out_loss = out + (long)NROWS * TAG_DIM;
    float* out_fidx = out_loss + 1;            // 131072 indices as f32

    // ws layout (~1.3 MB): scc | cbf(h-only) | cbT(f32 transpose) | list | count | partial
    char* wsb = (char*)d_ws;
    float*          scc     = (float*)(wsb);                     // 4 KB
    unsigned short* cbf     = (unsigned short*)(wsb + 4096);     // 256 KB
    float*          cbT     = (float*)(wsb + 266240);            // 512 KB
    int*            list    = (int*)(wsb + 790528);              // 512 KB
    int*            count   = (int*)(wsb + 1314816);             // 64 B
    double*         partial = (double*)(wsb + 1314880);          // 16 KB

    prep_kernel       <<<64, 256, 0, stream>>>(cb, scc, cbf, cbT, count);
    argmin_mfma_kernel<<<NROWS / 64, 64, 0, stream>>>(x, cbf, scc, out_fidx, list, count);
    exact_fix_kernel  <<<1024, 256, 0, stream>>>(x, cbT, scc, list, count, out_fidx);
    quant_kernel      <<<2048, 256, 0, stream>>>(x, cb, out_fidx, out, partial);
    loss_kernel       <<<1, 256, 0, stream>>>(partial, 2048, out_loss);
}

// Round 18
// 343.578 us; speedup vs baseline: 1.0053x; 1.0053x over previous
//
#include <hip/hip_runtime.h>

#define NUM_TAG 1024
#define TAG_DIM 128
#define NROWS   131072      // B*W = 128*1024
#define FLAG_M  5.5e-4f     // h-only margin, ~7 sigma (verified r14/r15/r17, absmax 0)
#define RPG     16          // rows per group in exact_fix
#define RF      4           // 16-row A fragments per wave (64 rows/wave)

typedef __attribute__((ext_vector_type(8))) short short8;
typedef __attribute__((ext_vector_type(4))) float f32x4;

// Exact 2-way bf16 split: x = h + m + (residual < 2^-16 |x|), h/m bf16-exact.
__device__ inline void split2(float xv, unsigned short& h, unsigned short& m) {
    unsigned xb = __float_as_uint(xv);
    unsigned hb = xb & 0xFFFF0000u;
    float r1 = xv - __uint_as_float(hb);        // Sterbenz-exact
    unsigned mb = __float_as_uint(r1) & 0xFFFF0000u;
    h = (unsigned short)(hb >> 16);
    m = (unsigned short)(mb >> 16);
}

// async global->LDS, 16B per lane (linear LDS dest = wave-uniform base + lane*16)
__device__ inline void gld_lds16(const void* g, void* l) {
    __builtin_amdgcn_global_load_lds(
        (const __attribute__((address_space(1))) void*)g,
        (__attribute__((address_space(3))) void*)l, 16, 0, 0);
}

// -------- fused prep: h-only frag codebook + fp32 transposed codebook + scc ----
// Chunk = 32 codes, h-only: 2 c x 4 s x 64 lanes x 8 elems = 4096 ushorts = 8 KB.
// 32 chunks = 256 KB. cbf[ch*4096 + ((c*4 + s)*64 + l)*8 + e]
//   = truncbf16(cb[ch*32 + c*16 + (l&15)][s*32 + (l>>4)*8 + e])
// cbT[d*1024 + k] = cb[k][d]   (fp32 transpose, r15/r16-verified, for exact_fix)
__global__ __launch_bounds__(256) void prep_kernel(
    const float* __restrict__ cb, float* __restrict__ scc,
    unsigned short* __restrict__ cbf, float* __restrict__ cbT,
    int* __restrict__ count)
{
    int t = blockIdx.x * 256 + threadIdx.x;   // 16384 threads
    if (t == 0) count[0] = 0;
    {
        int l  = t & 63;
        int s  = (t >> 6) & 3;
        int c  = (t >> 8) & 1;
        int ch = t >> 9;                       // 0..31
        int k  = ch * 32 + c * 16 + (l & 15);
        int d0 = s * 32 + (l >> 4) * 8;
        const float4* xp = reinterpret_cast<const float4*>(cb) + k * 32 + (d0 >> 2);
        float4 v0 = xp[0], v1 = xp[1];
        float xv[8] = {v0.x, v0.y, v0.z, v0.w, v1.x, v1.y, v1.z, v1.w};
        short8 hh;
#pragma unroll
        for (int e = 0; e < 8; ++e) {
            hh[e] = (short)(unsigned short)(__float_as_uint(xv[e]) >> 16);
            cbT[(d0 + e) * 1024 + k] = xv[e];
        }
        *reinterpret_cast<short8*>(cbf + (long)ch * 4096 + (((c * 4 + s) * 64 + l) * 8)) = hh;
    }
    if (t < NUM_TAG) {
        const float4* row = reinterpret_cast<const float4*>(cb) + t * (TAG_DIM / 4);
        float s = 0.f;
#pragma unroll
        for (int i = 0; i < TAG_DIM / 4; ++i) {
            float4 v = row[i];
            s += v.x * v.x; s += v.y * v.y; s += v.z * v.z; s += v.w * v.w;
        }
        scc[t] = s;
    }
}

// -------- pass A: (Ah+Am)xBh MFMA scores + top-2 + near-tie flag append --------
// r12/r16's verified no-barrier skeleton; h-only 32-code chunks processed as
// TWO SEQUENTIAL 16-code halves so only one Bh[4]+acc[RF] set is live at a
// time (peak regs ~223 < 256 -> no spill; r17's Bh[2][4]+acc[RF][2] was ~257
// and spilled, WRITE_SIZE 6 MB). Per chunk: vmcnt(8) wait -> reads c0 ->
// 32 MFMAs + fold c0 -> reads c1 -> lgkmcnt(0)+sched_barrier (WAR) ->
// restage ch+2 -> 32 MFMAs + fold c1. Score chain per (row,code) identical
// to r17 (refchecked); fold k-ascending preserved (c0 then c1).
__global__ __launch_bounds__(64, 2) void argmin_mfma_kernel(
    const float* __restrict__ x,
    const unsigned short* __restrict__ cbf,
    const float* __restrict__ scc,
    float* __restrict__ fidx_out,
    int* __restrict__ list, int* __restrict__ count)
{
    __shared__ __align__(16) unsigned short lds[2][4096];   // 2 x 8 KB
    __shared__ float scc_lds[NUM_TAG];                      // 4 KB  (20 KB total)

    const int l   = threadIdx.x & 63;
    const int l15 = l & 15;
    const int l4  = l >> 4;
    const int row0 = blockIdx.x * 64;

    const float4* gsrc = reinterpret_cast<const float4*>(cbf);  // chunk = 512 float4

    // ---- prologue staging: scc (4 loads) then chunks 0,1 (8+8) ----
#pragma unroll
    for (int i = 0; i < 4; ++i)
        gld_lds16(reinterpret_cast<const float4*>(scc) + i * 64 + l,
                  (void*)(scc_lds + (i * 64 + l) * 4));
#pragma unroll
    for (int i = 0; i < 8; ++i)
        gld_lds16(gsrc + i * 64 + l, (void*)&lds[0][(i * 64 + l) * 8]);
#pragma unroll
    for (int i = 0; i < 8; ++i)
        gld_lds16(gsrc + 512 + i * 64 + l, (void*)&lds[1][(i * 64 + l) * 8]);

    // ---- A fragments (these loads drain the whole vmcnt FIFO via split2 use) --
    short8 Ah[RF][4], Am[RF][4];
#pragma unroll
    for (int rf = 0; rf < RF; ++rf) {
        const float4* xp = reinterpret_cast<const float4*>(x) +
                           (long)(row0 + rf * 16 + l15) * 32 + l4 * 2;
#pragma unroll
        for (int s = 0; s < 4; ++s) {
            float4 v0 = xp[s * 8];
            float4 v1 = xp[s * 8 + 1];
            float xv[8] = {v0.x, v0.y, v0.z, v0.w, v1.x, v1.y, v1.z, v1.w};
#pragma unroll
            for (int e = 0; e < 8; ++e) {
                unsigned short h, m;
                split2(xv[e], h, m);
                Ah[rf][s][e] = (short)h;
                Am[rf][s][e] = (short)m;
            }
        }
    }

    float m1[RF][4], m2[RF][4]; int i1[RF][4];
#pragma unroll
    for (int rf = 0; rf < RF; ++rf)
#pragma unroll
        for (int r = 0; r < 4; ++r) { m1[rf][r] = 3.4e38f; m2[rf][r] = 3.4e38f; i1[rf][r] = 0; }

    for (int ch = 0; ch < 32; ++ch) {
        const int b = ch & 1;
        // current chunk guaranteed in LDS: <=8 outstanding leaves only next chunk
        if (ch < 31) { asm volatile("s_waitcnt vmcnt(8)" ::: "memory"); }
        else         { asm volatile("s_waitcnt vmcnt(0)" ::: "memory"); }
        __builtin_amdgcn_sched_barrier(0);

        // ---- half c=0: 4 ds_reads -> 32 MFMAs -> fold (covers c1 read latency)
        {
            short8 Bh[4];
#pragma unroll
            for (int s = 0; s < 4; ++s)
                Bh[s] = *reinterpret_cast<const short8*>(
                    &lds[b][(((0 * 4 + s) * 64 + l) * 8)]);
            const float sccv = scc_lds[ch * 32 + l15];

            f32x4 acc[RF];
#pragma unroll
            for (int rf = 0; rf < RF; ++rf) acc[rf] = (f32x4)0.f;
            // verified r14/r15/r17 order: s ascending, (Am,Bh) then (Ah,Bh)
#pragma unroll
            for (int s = 0; s < 4; ++s)
#pragma unroll
                for (int rf = 0; rf < RF; ++rf) {
                    acc[rf] = __builtin_amdgcn_mfma_f32_16x16x32_bf16(Am[rf][s], Bh[s], acc[rf], 0, 0, 0);
                    acc[rf] = __builtin_amdgcn_mfma_f32_16x16x32_bf16(Ah[rf][s], Bh[s], acc[rf], 0, 0, 0);
                }
            const int k = ch * 32 + l15;
#pragma unroll
            for (int rf = 0; rf < RF; ++rf)
#pragma unroll
                for (int r = 0; r < 4; ++r) {
                    float score = sccv - 2.0f * acc[rf][r];
                    m2[rf][r] = __builtin_amdgcn_fmed3f(score, m1[rf][r], m2[rf][r]);
                    i1[rf][r] = (score < m1[rf][r]) ? k : i1[rf][r];
                    m1[rf][r] = fminf(m1[rf][r], score);
                }
        }

        // ---- half c=1: 4 ds_reads; WAR fence + restage; 32 MFMAs -> fold ----
        {
            short8 Bh[4];
#pragma unroll
            for (int s = 0; s < 4; ++s)
                Bh[s] = *reinterpret_cast<const short8*>(
                    &lds[b][(((1 * 4 + s) * 64 + l) * 8)]);
            const float sccv = scc_lds[ch * 32 + 16 + l15];

            // ALL reads of buffer b landed in regs before overwrite (WAR)
            asm volatile("s_waitcnt lgkmcnt(0)" ::: "memory");
            __builtin_amdgcn_sched_barrier(0);

            if (ch + 2 < 32) {
                const float4* gp = gsrc + (ch + 2) * 512 + l;
#pragma unroll
                for (int i = 0; i < 8; ++i)
                    gld_lds16(gp + i * 64, (void*)&lds[b][(i * 64 + l) * 8]);
            }

            f32x4 acc[RF];
#pragma unroll
            for (int rf = 0; rf < RF; ++rf) acc[rf] = (f32x4)0.f;
#pragma unroll
            for (int s = 0; s < 4; ++s)
#pragma unroll
                for (int rf = 0; rf < RF; ++rf) {
                    acc[rf] = __builtin_amdgcn_mfma_f32_16x16x32_bf16(Am[rf][s], Bh[s], acc[rf], 0, 0, 0);
                    acc[rf] = __builtin_amdgcn_mfma_f32_16x16x32_bf16(Ah[rf][s], Bh[s], acc[rf], 0, 0, 0);
                }
            const int k = ch * 32 + 16 + l15;
#pragma unroll
            for (int rf = 0; rf < RF; ++rf)
#pragma unroll
                for (int r = 0; r < 4; ++r) {
                    float score = sccv - 2.0f * acc[rf][r];
                    m2[rf][r] = __builtin_amdgcn_fmed3f(score, m1[rf][r], m2[rf][r]);
                    i1[rf][r] = (score < m1[rf][r]) ? k : i1[rf][r];
                    m1[rf][r] = fminf(m1[rf][r], score);
                }
        }
    }

    // ---- cross-lane top-2 merge within each 16-lane col group ----
#pragma unroll
    for (int rf = 0; rf < RF; ++rf)
#pragma unroll
        for (int r = 0; r < 4; ++r) {
            float v1 = m1[rf][r], v2 = m2[rf][r]; int ii = i1[rf][r];
#pragma unroll
            for (int mk = 1; mk < 16; mk <<= 1) {
                float o1 = __shfl_xor(v1, mk, 64);
                float o2 = __shfl_xor(v2, mk, 64);
                int   oi = __shfl_xor(ii, mk, 64);
                float n2 = fminf(fminf(v2, o2), fmaxf(v1, o1));  // global 2nd-min
                if (o1 < v1 || (o1 == v1 && oi < ii)) { v1 = o1; ii = oi; }
                v2 = n2;
            }
            if (l15 == 0) {
                int row = row0 + rf * 16 + l4 * 4 + r;
                fidx_out[row] = (float)ii;
                if (v2 - v1 <= FLAG_M) {           // near-tie: append for exact rescore
                    int pos = atomicAdd(count, 1); // list order nondet; per-row results
                    list[pos] = row;               // independent -> output deterministic
                }
            }
        }
}

// -------- pass B: exact rescore, coalesced via transposed codebook (r15/r16) --
// Thread tid owns codes k = j*256+tid (j ascending -> in-thread ascending k).
// Per (row,code): fma chain in d-ascending order (one fma per d) == round-1
// recipe bit-exactly. dist = (sxx+scc) - 2*dot, tie -> lowest k (lex reduces).
__global__ __launch_bounds__(256) void exact_fix_kernel(
    const float* __restrict__ x, const float* __restrict__ cbT,
    const float* __restrict__ scc, const int* __restrict__ list,
    const int* __restrict__ count, float* __restrict__ fidx_out)
{
    __shared__ float Xs[RPG][TAG_DIM];   // 8 KB
    __shared__ float sxxs[RPG];
    __shared__ float wrv[RPG][4];
    __shared__ int   wri[RPG][4];
    __shared__ int   rows_s[RPG];

    const int tid  = threadIdx.x;
    const int lane = tid & 63;
    const int wv   = tid >> 6;
    const int nflag = count[0];
    const int ngroups = (nflag + RPG - 1) / RPG;

    for (int g = blockIdx.x; g < ngroups; g += gridDim.x) {
        const int nr = min(RPG, nflag - g * RPG);
        if (tid < RPG)
            rows_s[tid] = list[g * RPG + min(tid, nr - 1)];   // dup last for tail
        __syncthreads();
        // stage RPG rows x 32 float4 (coalesced)
        for (int t2 = tid; t2 < RPG * 32; t2 += 256) {
            int r = t2 >> 5, i = t2 & 31;
            reinterpret_cast<float4*>(&Xs[r][0])[i] =
                reinterpret_cast<const float4*>(x)[(long)rows_s[r] * 32 + i];
        }
        __syncthreads();
        if (tid < RPG) {   // per-row sxx, round-1 sequential order
            float s = 0.f;
            for (int i = 0; i < 32; ++i) {
                float4 v = reinterpret_cast<float4*>(&Xs[tid][0])[i];
                s += v.x * v.x; s += v.y * v.y; s += v.z * v.z; s += v.w * v.w;
            }
            sxxs[tid] = s;
        }
        __syncthreads();

        float acc[RPG][4];
#pragma unroll
        for (int r = 0; r < RPG; ++r)
#pragma unroll
            for (int j = 0; j < 4; ++j) acc[r][j] = 0.f;

        for (int d4 = 0; d4 < 32; ++d4) {
            float4 xq[RPG];
#pragma unroll
            for (int r = 0; r < RPG; ++r)
                xq[r] = reinterpret_cast<float4*>(&Xs[r][0])[d4];
#pragma unroll
            for (int e = 0; e < 4; ++e) {
                const int d = d4 * 4 + e;
                float c0 = cbT[d * 1024 + 0 * 256 + tid];   // coalesced
                float c1 = cbT[d * 1024 + 1 * 256 + tid];
                float c2 = cbT[d * 1024 + 2 * 256 + tid];
                float c3 = cbT[d * 1024 + 3 * 256 + tid];
#pragma unroll
                for (int r = 0; r < RPG; ++r) {
                    float xv = (e == 0) ? xq[r].x : (e == 1) ? xq[r].y
                             : (e == 2) ? xq[r].z : xq[r].w;
                    acc[r][0] += xv * c0;   // d-ascending fma chain (== round-1)
                    acc[r][1] += xv * c1;
                    acc[r][2] += xv * c2;
                    acc[r][3] += xv * c3;
                }
            }
        }

#pragma unroll
        for (int r = 0; r < RPG; ++r) {
            float bv = 3.4e38f; int bi = 0;
            const float sxxv = sxxs[r];
#pragma unroll
            for (int j = 0; j < 4; ++j) {
                int k = j * 256 + tid;             // in-thread ascending k
                float s1 = sxxv + scc[k];          // np: (sxx + scc)
                float dist = s1 - 2.0f * acc[r][j]; // np: ... - 2*dot
                if (dist < bv) { bv = dist; bi = k; }
            }
            // wave reduce (tie -> lowest k)
#pragma unroll
            for (int mk = 1; mk < 64; mk <<= 1) {
                float ov = __shfl_xor(bv, mk, 64);
                int   oi = __shfl_xor(bi, mk, 64);
                if (ov < bv || (ov == bv && oi < bi)) { bv = ov; bi = oi; }
            }
            if (lane == 0) { wrv[r][wv] = bv; wri[r][wv] = bi; }
        }
        __syncthreads();
        if (tid < RPG && tid < nr) {
            float bv = wrv[tid][0]; int bi = wri[tid][0];
#pragma unroll
            for (int e = 1; e < 4; ++e) {
                float v = wrv[tid][e]; int oi = wri[tid][e];
                if (v < bv || (v == bv && oi < bi)) { bv = v; bi = oi; }
            }
            fidx_out[rows_s[tid]] = (float)bi;
        }
        __syncthreads();
    }
}

// -------- phase 2: gather + STE output + loss partials --------
__global__ __launch_bounds__(256) void quant_kernel(
    const float* __restrict__ x, const float* __restrict__ cb,
    const float* __restrict__ fidx, float* __restrict__ out,
    double* __restrict__ partial)
{
    const int N4 = NROWS * (TAG_DIM / 4);
    double s = 0.0;
    for (int i = blockIdx.x * blockDim.x + threadIdx.x; i < N4; i += gridDim.x * blockDim.x) {
        int n = i >> 5;
        int d4 = i & 31;
        int k = (int)fidx[n];
        float4 xv = reinterpret_cast<const float4*>(x)[i];
        float4 qv = reinterpret_cast<const float4*>(cb)[k * 32 + d4];
        float dx = qv.x - xv.x, dy = qv.y - xv.y, dz = qv.z - xv.z, dw = qv.w - xv.w;
        float4 o;
        o.x = xv.x + dx; o.y = xv.y + dy; o.z = xv.z + dz; o.w = xv.w + dw;
        reinterpret_cast<float4*>(out)[i] = o;
        s += (double)dx * dx; s += (double)dy * dy; s += (double)dz * dz; s += (double)dw * dw;
    }
    __shared__ double sd[256];
    sd[threadIdx.x] = s;
    __syncthreads();
    for (int off = 128; off > 0; off >>= 1) {
        if (threadIdx.x < (unsigned)off) sd[threadIdx.x] += sd[threadIdx.x + off];
        __syncthreads();
    }
    if (threadIdx.x == 0) partial[blockIdx.x] = sd[0];
}

__global__ __launch_bounds__(256) void loss_kernel(
    const double* __restrict__ partial, int n, float* __restrict__ out_loss)
{
    __shared__ double sd[256];
    double s = 0.0;
    for (int i = threadIdx.x; i < n; i += 256) s += partial[i];
    sd[threadIdx.x] = s;
    __syncthreads();
    for (int off = 128; off > 0; off >>= 1) {
        if (threadIdx.x < (unsigned)off) sd[threadIdx.x] += sd[threadIdx.x + off];
        __syncthreads();
    }
    if (threadIdx.x == 0) {
        double mean = sd[0] / (double)((long long)NROWS * TAG_DIM);
        out_loss[0] = (float)(mean + 0.25 * mean);
    }
}

extern "C" void kernel_launch(void* const* d_in, const int* in_sizes, int n_in,
                              void* d_out, int out_size, void* d_ws, size_t ws_size,
                              hipStream_t stream) {
    const float* x  = (const float*)d_in[0];   // [131072][128]
    const float* cb = (const float*)d_in[1];   // [1024][128]
    float* out      = (float*)d_out;
    float* out_loss = out + (long)NROWS * TAG_DIM;
    float* out_fidx = out_loss + 1;            // 131072 indices as f32

    // ws layout (~1.3 MB): scc | cbf(h-only) | cbT(f32 transpose) | list | count | partial
    char* wsb = (char*)d_ws;
    float*          scc     = (float*)(wsb);                     // 4 KB
    unsigned short* cbf     = (unsigned short*)(wsb + 4096);     // 256 KB
    float*          cbT     = (float*)(wsb + 266240);            // 512 KB
    int*            list    = (int*)(wsb + 790528);              // 512 KB
    int*            count   = (int*)(wsb + 1314816);             // 64 B
    double*         partial = (double*)(wsb + 1314880);          // 16 KB

    prep_kernel       <<<64, 256, 0, stream>>>(cb, scc, cbf, cbT, count);
    argmin_mfma_kernel<<<NROWS / 64, 64, 0, stream>>>(x, cbf, scc, out_fidx, list, count);
    exact_fix_kernel  <<<1024, 256, 0, stream>>>(x, cbT, scc, list, count, out_fidx);
    quant_kernel      <<<2048, 256, 0, stream>>>(x, cb, out_fidx, out, partial);
    loss_kernel       <<<1, 256, 0, stream>>>(partial, 2048, out_loss);
}

// Round 19
// 199.236 us; speedup vs baseline: 1.7337x; 1.7245x over previous
//
#include <hip/hip_runtime.h>

#define NUM_TAG 1024
#define TAG_DIM 128
#define NROWS   131072      // B*W = 128*1024
#define FLAG_M  1.25e-4f    // 3-product margin (verified r3-r13/r16, absmax 0)
#define RPG     16          // rows per group in exact_fix
#define RF      4           // 16-row A fragments per wave (64 rows/wave)

typedef __attribute__((ext_vector_type(8))) short short8;
typedef __attribute__((ext_vector_type(4))) float f32x4;

// Exact 2-way bf16 split: x = h + m + (residual < 2^-16 |x|), h/m bf16-exact.
__device__ inline void split2(float xv, unsigned short& h, unsigned short& m) {
    unsigned xb = __float_as_uint(xv);
    unsigned hb = xb & 0xFFFF0000u;
    float r1 = xv - __uint_as_float(hb);        // Sterbenz-exact
    unsigned mb = __float_as_uint(r1) & 0xFFFF0000u;
    h = (unsigned short)(hb >> 16);
    m = (unsigned short)(mb >> 16);
}

// async global->LDS, 16B per lane (linear LDS dest = wave-uniform base + lane*16)
__device__ inline void gld_lds16(const void* g, void* l) {
    __builtin_amdgcn_global_load_lds(
        (const __attribute__((address_space(1))) void*)g,
        (__attribute__((address_space(3))) void*)l, 16, 0, 0);
}

// -------- fused prep: h+m frag codebook + fp32 transposed codebook + scc ------
// cbf chunk = 16 codes: 2 arrays (h,m) x 4 s x 64 lanes x 8 elems
//       = 4096 ushorts = 8 KB. 64 chunks = 512 KB.  (r12/r16 layout, verified)
// cbf[ch*4096 + ((arr*4 + s)*64 + l)*8 + e]
//   = split(cb[ch*16 + (l&15)][s*32 + (l>>4)*8 + e])
// cbT[d*1024 + k] = cb[k][d]   (fp32 transpose, r15/r16-verified, for exact_fix)
__global__ __launch_bounds__(256) void prep_kernel(
    const float* __restrict__ cb, float* __restrict__ scc,
    unsigned short* __restrict__ cbf, float* __restrict__ cbT,
    int* __restrict__ count)
{
    int t = blockIdx.x * 256 + threadIdx.x;   // 16384 threads
    if (t == 0) count[0] = 0;
    {
        int l  = t & 63;
        int s  = (t >> 6) & 3;
        int ch = t >> 8;                       // 0..63
        int k  = ch * 16 + (l & 15);
        int d0 = s * 32 + (l >> 4) * 8;
        const float4* xp = reinterpret_cast<const float4*>(cb) + k * 32 + (d0 >> 2);
        float4 v0 = xp[0], v1 = xp[1];
        float xv[8] = {v0.x, v0.y, v0.z, v0.w, v1.x, v1.y, v1.z, v1.w};
        short8 hh, mm;
#pragma unroll
        for (int e = 0; e < 8; ++e) {
            unsigned short h, m;
            split2(xv[e], h, m);
            hh[e] = (short)h; mm[e] = (short)m;
            cbT[(d0 + e) * 1024 + k] = xv[e];
        }
        long baseh = (long)ch * 4096 + (((0 * 4) + s) * 64 + l) * 8;
        long basem = (long)ch * 4096 + (((1 * 4) + s) * 64 + l) * 8;
        *reinterpret_cast<short8*>(cbf + baseh) = hh;
        *reinterpret_cast<short8*>(cbf + basem) = mm;
    }
    if (t < NUM_TAG) {
        const float4* row = reinterpret_cast<const float4*>(cb) + t * (TAG_DIM / 4);
        float s = 0.f;
#pragma unroll
        for (int i = 0; i < TAG_DIM / 4; ++i) {
            float4 v = row[i];
            s += v.x * v.x; s += v.y * v.y; s += v.z * v.z; s += v.w * v.w;
        }
        scc[t] = s;
    }
}

// -------- pass A: split-bf16 MFMA scores + top-2 + near-tie flag append --------
// r12/r16 VERBATIM (measured 139-144 us, absmax 0.0): ONE wave per block
// (64 rows, RF=4), 2048 blocks, ZERO barriers. gld_lds double buffer of 8 KB
// chunks; counted vmcnt(8) (never 0 in-loop, T4); lgkmcnt(0) before re-stage
// (WAR); sched_barrier(0) fences (rule #18). scc from LDS (lgkm path).
// Per-(row,code) score sequence bit-identical to rounds 3-13/16.
__global__ __launch_bounds__(64, 2) void argmin_mfma_kernel(
    const float* __restrict__ x,
    const unsigned short* __restrict__ cbf,
    const float* __restrict__ scc,
    float* __restrict__ fidx_out,
    int* __restrict__ list, int* __restrict__ count)
{
    __shared__ __align__(16) unsigned short lds[2][4096];   // 2 x 8 KB
    __shared__ float scc_lds[NUM_TAG];                      // 4 KB  (20 KB total)

    const int l   = threadIdx.x & 63;
    const int l15 = l & 15;
    const int l4  = l >> 4;
    const int row0 = blockIdx.x * 64;

    const float4* gsrc = reinterpret_cast<const float4*>(cbf);  // chunk = 512 float4

    // ---- prologue staging: scc (4 loads) then chunks 0,1 (8+8) ----
#pragma unroll
    for (int i = 0; i < 4; ++i)
        gld_lds16(reinterpret_cast<const float4*>(scc) + i * 64 + l,
                  (void*)(scc_lds + (i * 64 + l) * 4));
#pragma unroll
    for (int i = 0; i < 8; ++i)
        gld_lds16(gsrc + i * 64 + l, (void*)&lds[0][(i * 64 + l) * 8]);
#pragma unroll
    for (int i = 0; i < 8; ++i)
        gld_lds16(gsrc + 512 + i * 64 + l, (void*)&lds[1][(i * 64 + l) * 8]);

    // ---- A fragments (these loads drain the whole vmcnt FIFO via split2 use) --
    short8 Ah[RF][4], Am[RF][4];
#pragma unroll
    for (int rf = 0; rf < RF; ++rf) {
        const float4* xp = reinterpret_cast<const float4*>(x) +
                           (long)(row0 + rf * 16 + l15) * 32 + l4 * 2;
#pragma unroll
        for (int s = 0; s < 4; ++s) {
            float4 v0 = xp[s * 8];
            float4 v1 = xp[s * 8 + 1];
            float xv[8] = {v0.x, v0.y, v0.z, v0.w, v1.x, v1.y, v1.z, v1.w};
#pragma unroll
            for (int e = 0; e < 8; ++e) {
                unsigned short h, m;
                split2(xv[e], h, m);
                Ah[rf][s][e] = (short)h;
                Am[rf][s][e] = (short)m;
            }
        }
    }

    float m1[RF][4], m2[RF][4]; int i1[RF][4];
#pragma unroll
    for (int rf = 0; rf < RF; ++rf)
#pragma unroll
        for (int r = 0; r < 4; ++r) { m1[rf][r] = 3.4e38f; m2[rf][r] = 3.4e38f; i1[rf][r] = 0; }

    for (int ch = 0; ch < 64; ++ch) {
        const int b = ch & 1;
        // current chunk guaranteed in LDS: <=8 outstanding leaves only next chunk
        if (ch < 63) { asm volatile("s_waitcnt vmcnt(8)" ::: "memory"); }
        else         { asm volatile("s_waitcnt vmcnt(0)" ::: "memory"); }
        __builtin_amdgcn_sched_barrier(0);

        // LDS -> registers: 8 x ds_read_b128 (B frags) + 1 x ds_read_b32 (scc)
        short8 Bh[4], Bm[4];
#pragma unroll
        for (int s = 0; s < 4; ++s) {
            Bh[s] = *reinterpret_cast<const short8*>(&lds[b][(((0 * 4) + s) * 64 + l) * 8]);
            Bm[s] = *reinterpret_cast<const short8*>(&lds[b][(((1 * 4) + s) * 64 + l) * 8]);
        }
        const float sccv = scc_lds[ch * 16 + l15];

        // all LDS reads landed in regs before we overwrite this buffer (WAR)
        asm volatile("s_waitcnt lgkmcnt(0)" ::: "memory");
        __builtin_amdgcn_sched_barrier(0);

        // re-stage this buffer with chunk ch+2
        if (ch + 2 < 64) {
            const float4* gp = gsrc + (ch + 2) * 512 + l;
#pragma unroll
            for (int i = 0; i < 8; ++i)
                gld_lds16(gp + i * 64, (void*)&lds[b][(i * 64 + l) * 8]);
        }

        f32x4 acc[RF];
#pragma unroll
        for (int rf = 0; rf < RF; ++rf) acc[rf] = (f32x4)0.f;

        // per-acc order: s ascending, (Ah,Bm),(Am,Bh),(Ah,Bh) — bit-identical
#pragma unroll
        for (int s = 0; s < 4; ++s)
#pragma unroll
            for (int rf = 0; rf < RF; ++rf) {
                acc[rf] = __builtin_amdgcn_mfma_f32_16x16x32_bf16(Ah[rf][s], Bm[s], acc[rf], 0, 0, 0);
                acc[rf] = __builtin_amdgcn_mfma_f32_16x16x32_bf16(Am[rf][s], Bh[s], acc[rf], 0, 0, 0);
                acc[rf] = __builtin_amdgcn_mfma_f32_16x16x32_bf16(Ah[rf][s], Bh[s], acc[rf], 0, 0, 0);
            }

        // fold into running top-2 (med3 form, verified r9-r16); k = ch*16+l15
        const int k = ch * 16 + l15;
#pragma unroll
        for (int rf = 0; rf < RF; ++rf)
#pragma unroll
            for (int r = 0; r < 4; ++r) {
                float score = sccv - 2.0f * acc[rf][r];
                m2[rf][r] = __builtin_amdgcn_fmed3f(score, m1[rf][r], m2[rf][r]);
                i1[rf][r] = (score < m1[rf][r]) ? k : i1[rf][r];
                m1[rf][r] = fminf(m1[rf][r], score);
            }
    }

    // ---- cross-lane top-2 merge within each 16-lane col group ----
#pragma unroll
    for (int rf = 0; rf < RF; ++rf)
#pragma unroll
        for (int r = 0; r < 4; ++r) {
            float v1 = m1[rf][r], v2 = m2[rf][r]; int ii = i1[rf][r];
#pragma unroll
            for (int mk = 1; mk < 16; mk <<= 1) {
                float o1 = __shfl_xor(v1, mk, 64);
                float o2 = __shfl_xor(v2, mk, 64);
                int   oi = __shfl_xor(ii, mk, 64);
                float n2 = fminf(fminf(v2, o2), fmaxf(v1, o1));  // global 2nd-min
                if (o1 < v1 || (o1 == v1 && oi < ii)) { v1 = o1; ii = oi; }
                v2 = n2;
            }
            if (l15 == 0) {
                int row = row0 + rf * 16 + l4 * 4 + r;
                fidx_out[row] = (float)ii;
                if (v2 - v1 <= FLAG_M) {           // near-tie: append for exact rescore
                    int pos = atomicAdd(count, 1); // list order nondet; per-row results
                    list[pos] = row;               // independent -> output deterministic
                }
            }
        }
}

// -------- pass B: exact rescore, coalesced via transposed codebook (r15/r16) --
// Thread tid owns codes k = j*256+tid (j ascending -> in-thread ascending k).
// Per (row,code): fma chain in d-ascending order (one fma per d) == round-1
// recipe bit-exactly. dist = (sxx+scc) - 2*dot, tie -> lowest k (lex reduces).
__global__ __launch_bounds__(256) void exact_fix_kernel(
    const float* __restrict__ x, const float* __restrict__ cbT,
    const float* __restrict__ scc, const int* __restrict__ list,
    const int* __restrict__ count, float* __restrict__ fidx_out)
{
    __shared__ float Xs[RPG][TAG_DIM];   // 8 KB
    __shared__ float sxxs[RPG];
    __shared__ float wrv[RPG][4];
    __shared__ int   wri[RPG][4];
    __shared__ int   rows_s[RPG];

    const int tid  = threadIdx.x;
    const int lane = tid & 63;
    const int wv   = tid >> 6;
    const int nflag = count[0];
    const int ngroups = (nflag + RPG - 1) / RPG;

    for (int g = blockIdx.x; g < ngroups; g += gridDim.x) {
        const int nr = min(RPG, nflag - g * RPG);
        if (tid < RPG)
            rows_s[tid] = list[g * RPG + min(tid, nr - 1)];   // dup last for tail
        __syncthreads();
        // stage RPG rows x 32 float4 (coalesced)
        for (int t2 = tid; t2 < RPG * 32; t2 += 256) {
            int r = t2 >> 5, i = t2 & 31;
            reinterpret_cast<float4*>(&Xs[r][0])[i] =
                reinterpret_cast<const float4*>(x)[(long)rows_s[r] * 32 + i];
        }
        __syncthreads();
        if (tid < RPG) {   // per-row sxx, round-1 sequential order
            float s = 0.f;
            for (int i = 0; i < 32; ++i) {
                float4 v = reinterpret_cast<float4*>(&Xs[tid][0])[i];
                s += v.x * v.x; s += v.y * v.y; s += v.z * v.z; s += v.w * v.w;
            }
            sxxs[tid] = s;
        }
        __syncthreads();

        float acc[RPG][4];
#pragma unroll
        for (int r = 0; r < RPG; ++r)
#pragma unroll
            for (int j = 0; j < 4; ++j) acc[r][j] = 0.f;

        for (int d4 = 0; d4 < 32; ++d4) {
            float4 xq[RPG];
#pragma unroll
            for (int r = 0; r < RPG; ++r)
                xq[r] = reinterpret_cast<float4*>(&Xs[r][0])[d4];
#pragma unroll
            for (int e = 0; e < 4; ++e) {
                const int d = d4 * 4 + e;
                float c0 = cbT[d * 1024 + 0 * 256 + tid];   // coalesced
                float c1 = cbT[d * 1024 + 1 * 256 + tid];
                float c2 = cbT[d * 1024 + 2 * 256 + tid];
                float c3 = cbT[d * 1024 + 3 * 256 + tid];
#pragma unroll
                for (int r = 0; r < RPG; ++r) {
                    float xv = (e == 0) ? xq[r].x : (e == 1) ? xq[r].y
                             : (e == 2) ? xq[r].z : xq[r].w;
                    acc[r][0] += xv * c0;   // d-ascending fma chain (== round-1)
                    acc[r][1] += xv * c1;
                    acc[r][2] += xv * c2;
                    acc[r][3] += xv * c3;
                }
            }
        }

#pragma unroll
        for (int r = 0; r < RPG; ++r) {
            float bv = 3.4e38f; int bi = 0;
            const float sxxv = sxxs[r];
#pragma unroll
            for (int j = 0; j < 4; ++j) {
                int k = j * 256 + tid;             // in-thread ascending k
                float s1 = sxxv + scc[k];          // np: (sxx + scc)
                float dist = s1 - 2.0f * acc[r][j]; // np: ... - 2*dot
                if (dist < bv) { bv = dist; bi = k; }
            }
            // wave reduce (tie -> lowest k)
#pragma unroll
            for (int mk = 1; mk < 64; mk <<= 1) {
                float ov = __shfl_xor(bv, mk, 64);
                int   oi = __shfl_xor(bi, mk, 64);
                if (ov < bv || (ov == bv && oi < bi)) { bv = ov; bi = oi; }
            }
            if (lane == 0) { wrv[r][wv] = bv; wri[r][wv] = bi; }
        }
        __syncthreads();
        if (tid < RPG && tid < nr) {
            float bv = wrv[tid][0]; int bi = wri[tid][0];
#pragma unroll
            for (int e = 1; e < 4; ++e) {
                float v = wrv[tid][e]; int oi = wri[tid][e];
                if (v < bv || (v == bv && oi < bi)) { bv = v; bi = oi; }
            }
            fidx_out[rows_s[tid]] = (float)bi;
        }
        __syncthreads();
    }
}

// -------- phase 2: gather + STE output + loss partials --------
__global__ __launch_bounds__(256) void quant_kernel(
    const float* __restrict__ x, const float* __restrict__ cb,
    const float* __restrict__ fidx, float* __restrict__ out,
    double* __restrict__ partial)
{
    const int N4 = NROWS * (TAG_DIM / 4);
    double s = 0.0;
    for (int i = blockIdx.x * blockDim.x + threadIdx.x; i < N4; i += gridDim.x * blockDim.x) {
        int n = i >> 5;
        int d4 = i & 31;
        int k = (int)fidx[n];
        float4 xv = reinterpret_cast<const float4*>(x)[i];
        float4 qv = reinterpret_cast<const float4*>(cb)[k * 32 + d4];
        float dx = qv.x - xv.x, dy = qv.y - xv.y, dz = qv.z - xv.z, dw = qv.w - xv.w;
        float4 o;
        o.x = xv.x + dx; o.y = xv.y + dy; o.z = xv.z + dz; o.w = xv.w + dw;
        reinterpret_cast<float4*>(out)[i] = o;
        s += (double)dx * dx; s += (double)dy * dy; s += (double)dz * dz; s += (double)dw * dw;
    }
    __shared__ double sd[256];
    sd[threadIdx.x] = s;
    __syncthreads();
    for (int off = 128; off > 0; off >>= 1) {
        if (threadIdx.x < (unsigned)off) sd[threadIdx.x] += sd[threadIdx.x + off];
        __syncthreads();
    }
    if (threadIdx.x == 0) partial[blockIdx.x] = sd[0];
}

__global__ __launch_bounds__(256) void loss_kernel(
    const double* __restrict__ partial, int n, float* __restrict__ out_loss)
{
    __shared__ double sd[256];
    double s = 0.0;
    for (int i = threadIdx.x; i < n; i += 256) s += partial[i];
    sd[threadIdx.x] = s;
    __syncthreads();
    for (int off = 128; off > 0; off >>= 1) {
        if (threadIdx.x < (unsigned)off) sd[threadIdx.x] += sd[threadIdx.x + off];
        __syncthreads();
    }
    if (threadIdx.x == 0) {
        double mean = sd[0] / (double)((long long)NROWS * TAG_DIM);
        out_loss[0] = (float)(mean + 0.25 * mean);
    }
}

extern "C" void kernel_launch(void* const* d_in, const int* in_sizes, int n_in,
                              void* d_out, int out_size, void* d_ws, size_t ws_size,
                              hipStream_t stream) {
    const float* x  = (const float*)d_in[0];   // [131072][128]
    const float* cb = (const float*)d_in[1];   // [1024][128]
    float* out      = (float*)d_out;
    float* out_loss = out + (long)NROWS * TAG_DIM;
    float* out_fidx = out_loss + 1;            // 131072 indices as f32

    // ws layout (~1.55 MB): scc | cbf(h+m) | cbT(f32 transpose) | list | count | partial
    char* wsb = (char*)d_ws;
    float*          scc     = (float*)(wsb);                     // 4 KB
    unsigned short* cbf     = (unsigned short*)(wsb + 4096);     // 512 KB
    float*          cbT     = (float*)(wsb + 528384);            // 512 KB
    int*            list    = (int*)(wsb + 1052672);             // 512 KB
    int*            count   = (int*)(wsb + 1576960);             // 64 B
    double*         partial = (double*)(wsb + 1577024);          // 16 KB

    prep_kernel       <<<64, 256, 0, stream>>>(cb, scc, cbf, cbT, count);
    argmin_mfma_kernel<<<NROWS / 64, 64, 0, stream>>>(x, cbf, scc, out_fidx, list, count);
    exact_fix_kernel  <<<1024, 256, 0, stream>>>(x, cbT, scc, list, count, out_fidx);
    quant_kernel      <<<2048, 256, 0, stream>>>(x, cb, out_fidx, out, partial);
    loss_kernel       <<<1, 256, 0, stream>>>(partial, 2048, out_loss);
}